// Round 2
// 472.165 us; speedup vs baseline: 1.1650x; 1.1650x over previous
//
#include <hip/hip_runtime.h>
#include <hip/hip_bf16.h>
#include <stdint.h>

#define NEG_BIG (-1e24f)

typedef __attribute__((ext_vector_type(8))) short bf16x8;
typedef __attribute__((ext_vector_type(4))) float f32x4;

#define AS1 __attribute__((address_space(1)))
#define AS3 __attribute__((address_space(3)))

__device__ __forceinline__ void gload_lds16(const void* g, void* l) {
    __builtin_amdgcn_global_load_lds((AS1 unsigned*)g, (AS3 unsigned*)l, 16, 0, 0);
}

__device__ __forceinline__ unsigned short f2bf(float f) {
    union { float f; unsigned u; } v; v.f = f;
    return (unsigned short)((v.u + 0x7FFFu + ((v.u >> 16) & 1u)) >> 16);
}

// ---------------------------------------------------------------------------
// K0: detect padding_mask storage dtype from its bit patterns.
// flag: 0 = int32 {0,1}, 1 = uint8 bytes, 2 = float32 {0.0,1.0}
__global__ void detect_mask_kernel(const unsigned* pm, int* flag) {
    __shared__ int notI, notF;
    if (threadIdx.x == 0) { notI = 0; notF = 0; }
    __syncthreads();
    int li = 0, lf = 0;
    for (int i = threadIdx.x; i < 8192; i += 256) {
        unsigned v = pm[i];
        if (v > 1u) li = 1;
        if (v != 0u && v != 0x3F800000u) lf = 1;
    }
    if (li) atomicOr(&notI, 1);
    if (lf) atomicOr(&notF, 1);
    __syncthreads();
    if (threadIdx.x == 0) *flag = notI ? (notF ? 1 : 2) : 0;
}

// ---------------------------------------------------------------------------
// K1 (v4): 1024-thread blocks (16 waves): 4 output-groups x 4 K-slices.
// Each wave: lane = row (64 rows/block), accumulates its 8 outputs over a
// 16-col sub-slice of every 64-col chunk; LDS tree-reduce across slices at
// the end. Register prefetch of next chunk's x overlaps HBM latency with
// compute. Exact fp32 q/k (score sign thresholds on masked rows).
// Occupancy: 2 blocks/CU x 16 waves = 32 waves/CU (vs 8 before).
__global__ __launch_bounds__(1024, 8)
void qk_conv_kernel(const float* __restrict__ x,
                    const float* __restrict__ Wq, const float* __restrict__ bq,
                    const float* __restrict__ Wk, const float* __restrict__ bk,
                    const void* __restrict__ pm, const int* __restrict__ pmflag,
                    unsigned short* __restrict__ xbf,
                    float* __restrict__ qo, float* __restrict__ ko) {
    // union: xs[64*65] staging (16.6KB)  |  red[4][64][33] partials (33.8KB)
    __shared__ float smem[4 * 64 * 33];
    float* xs = smem;
    const int tid = threadIdx.x;
    const int r0 = blockIdx.x * 64;
    const int lane = tid & 63;
    const int wv = __builtin_amdgcn_readfirstlane(tid >> 6);  // 0..15
    const int g = wv & 3;              // 0,1 = q-halves; 2,3 = k-halves
    const int sl = wv >> 2;            // K-slice 0..3 (16 cols of each chunk)
    const int jb = (g & 1) * 8;
    const int d0 = sl * 16;
    const float* __restrict__ W = (g < 2) ? Wq : Wk;

    const int sr = tid >> 4;           // staging row 0..63
    const int sd = (tid & 15) * 4;     // staging col within chunk
    const float* __restrict__ xp = x + (size_t)(r0 + sr) * 1024 + sd;
    unsigned short* __restrict__ xbp = xbf + (size_t)(r0 + sr) * 1024 + sd;

    float acc[8];
#pragma unroll
    for (int j = 0; j < 8; j++) acc[j] = 0.f;

    float4 xv = *(const float4*)xp;    // prefetch chunk 0
    for (int c0 = 0; c0 < 1024; c0 += 64) {
        // ---- stage current chunk into LDS; fused bf16 convert/store
        uint2 pk;
        pk.x = (unsigned)f2bf(xv.x) | ((unsigned)f2bf(xv.y) << 16);
        pk.y = (unsigned)f2bf(xv.z) | ((unsigned)f2bf(xv.w) << 16);
        *(uint2*)(xbp + c0) = pk;
        xs[sr * 65 + sd + 0] = xv.x;
        xs[sr * 65 + sd + 1] = xv.y;
        xs[sr * 65 + sd + 2] = xv.z;
        xs[sr * 65 + sd + 3] = xv.w;
        __syncthreads();
        // issue next chunk's global load now; it flies under the compute
        if (c0 + 64 < 1024) xv = *(const float4*)(xp + c0 + 64);
        // ---- accumulate this wave's 16-col sub-slice
        const float* __restrict__ wrow = W + (size_t)(c0 + d0) * 16 + jb;
        const float* __restrict__ xrow = xs + lane * 65 + d0;
#pragma unroll 4
        for (int dd = 0; dd < 16; dd++) {
            const float xvv = xrow[dd];
            const float* __restrict__ w = wrow + (size_t)dd * 16;
#pragma unroll
            for (int j = 0; j < 8; j++) acc[j] = fmaf(xvv, w[j], acc[j]);
        }
        __syncthreads();
    }

    // ---- cross-slice reduction through LDS (stride 33 -> 2-way free banks)
    float* red = smem;
    const int cb = jb + (g >> 1) * 16;      // col base 0/8/16/24
    {
        float* rr = red + ((size_t)(sl * 64 + lane)) * 33 + cb;
#pragma unroll
        for (int j = 0; j < 8; j++) rr[j] = acc[j];
    }
    __syncthreads();

    // ---- epilogue: each thread finishes one q element + one k element
    const int row = tid >> 4;
    const int c = tid & 15;
    const int grow = r0 + row;
    const float qv = red[(size_t)row * 33 + c]
                   + red[(size_t)(64 + row) * 33 + c]
                   + red[(size_t)(128 + row) * 33 + c]
                   + red[(size_t)(192 + row) * 33 + c] + bq[c];
    qo[(size_t)grow * 16 + c] = qv;
    const int flag = *pmflag;
    bool mk;
    if (flag == 1) mk = ((const unsigned char*)pm)[grow] != 0;
    else           mk = ((const unsigned*)pm)[grow] != 0;
    float kv;
    if (mk) {
        kv = NEG_BIG;
    } else {
        kv = red[(size_t)row * 33 + 16 + c]
           + red[(size_t)(64 + row) * 33 + 16 + c]
           + red[(size_t)(128 + row) * 33 + 16 + c]
           + red[(size_t)(192 + row) * 33 + 16 + c] + bk[c];
    }
    ko[(size_t)grow * 16 + c] = kv;
}

// ---------------------------------------------------------------------------
// K2: WvT[n][k] = bf16(Wv[k][n])  (B-operand layout for MFMA GEMM)
__global__ void wvt_kernel(const float* __restrict__ Wv, unsigned short* __restrict__ WvT) {
    __shared__ float tile[32][33];
    const int k0 = blockIdx.x * 32, n0 = blockIdx.y * 32;
    const int tid = threadIdx.x;
#pragma unroll
    for (int i = 0; i < 4; i++) {
        int idx = i * 256 + tid;
        int r = idx >> 5, c = idx & 31;
        tile[r][c] = Wv[(size_t)(k0 + r) * 1024 + n0 + c];
    }
    __syncthreads();
#pragma unroll
    for (int i = 0; i < 4; i++) {
        int idx = i * 256 + tid;
        int r = idx >> 5, c = idx & 31;
        WvT[(size_t)(n0 + r) * 1024 + k0 + c] = f2bf(tile[c][r]);
    }
}

// ---------------------------------------------------------------------------
// K3: v = xbf @ WvT + bv, output DIRECTLY transposed: vT[b][e][s].
// XCD swizzle: XCD c owns m-tiles c*32..c*32+31; for each m-tile the 8
// n-tiles are consecutive in dispatch order (A tile + B stays in that L2).
__global__ __launch_bounds__(256, 2)
void vgemm_kernel(const unsigned short* __restrict__ A,   // [32768][1024] bf16
                  const unsigned short* __restrict__ Bt,  // [1024][1024] bf16 (n-major)
                  const float* __restrict__ bias,
                  unsigned short* __restrict__ vTg) {     // [64][1024][512] bf16
    __shared__ __align__(16) unsigned short smem[17408];  // As(4096)+Bs(4096) | vt(128*136)
    unsigned short* As = smem;
    unsigned short* Bs = smem + 4096;
    const int bid = blockIdx.x;
    const int c = bid & 7;
    const int g = bid >> 3;
    const int mt = c * 32 + (g >> 3);
    const int nt = g & 7;
    const int m0 = mt * 128;
    const int n0 = nt * 128;
    const int tid = threadIdx.x;
    const int lane = tid & 63;
    const int wave = tid >> 6;
    const int wm = (wave & 1) * 64;
    const int wn = (wave >> 1) * 64;
    const int l15 = lane & 15;
    const int quad = lane >> 4;
    const int arow = tid >> 2;
    const int acol = (tid & 3) * 8;
    f32x4 acc[4][4];
#pragma unroll
    for (int i = 0; i < 4; i++)
#pragma unroll
        for (int j = 0; j < 4; j++)
#pragma unroll
            for (int r = 0; r < 4; r++) acc[i][j][r] = 0.f;

    for (int k0 = 0; k0 < 1024; k0 += 32) {
        gload_lds16(A + (size_t)(m0 + arow) * 1024 + k0 + acol, As + tid * 8);
        gload_lds16(A + (size_t)(m0 + 64 + arow) * 1024 + k0 + acol, As + 2048 + tid * 8);
        gload_lds16(Bt + (size_t)(n0 + arow) * 1024 + k0 + acol, Bs + tid * 8);
        gload_lds16(Bt + (size_t)(n0 + 64 + arow) * 1024 + k0 + acol, Bs + 2048 + tid * 8);
        __syncthreads();
        bf16x8 af[4], bfr[4];
#pragma unroll
        for (int i = 0; i < 4; i++) {
            af[i]  = *(const bf16x8*)(As + (wm + i * 16 + l15) * 32 + quad * 8);
            bfr[i] = *(const bf16x8*)(Bs + (wn + i * 16 + l15) * 32 + quad * 8);
        }
#pragma unroll
        for (int i = 0; i < 4; i++)
#pragma unroll
            for (int j = 0; j < 4; j++)
                acc[i][j] = __builtin_amdgcn_mfma_f32_16x16x32_bf16(af[i], bfr[j], acc[i][j], 0, 0, 0);
        __syncthreads();
    }
    // epilogue: bias + transpose through LDS, store vT coalesced
    unsigned short* vt = smem;  // reuse (safe: sync above after last reads)
#pragma unroll
    for (int j = 0; j < 4; j++) {
        const int e_local = wn + j * 16 + l15;
        const float bb = bias[n0 + e_local];
#pragma unroll
        for (int i = 0; i < 4; i++) {
            const int s_base = wm + i * 16 + quad * 4;
            unsigned short h0 = f2bf(acc[i][j][0] + bb);
            unsigned short h1 = f2bf(acc[i][j][1] + bb);
            unsigned short h2 = f2bf(acc[i][j][2] + bb);
            unsigned short h3 = f2bf(acc[i][j][3] + bb);
            uint2 u;
            u.x = (unsigned)h0 | ((unsigned)h1 << 16);
            u.y = (unsigned)h2 | ((unsigned)h3 << 16);
            *(uint2*)(vt + e_local * 136 + s_base) = u;
        }
    }
    __syncthreads();
    const int b = m0 >> 9;
    const int sbase = m0 & 511;
#pragma unroll
    for (int p = 0; p < 8; p++) {
        const int idx = p * 256 + tid;
        const int e = idx >> 4;
        const int s8 = (idx & 15) * 8;
        uint4 val = *(const uint4*)(vt + e * 136 + s8);
        *(uint4*)(vTg + ((size_t)b * 1024 + n0 + e) * 512 + sbase + s8) = val;
    }
}

// ---------------------------------------------------------------------------
// K5a: fp32 scores (q.k*4, causal -1e24) + 2-pass softmax.
// Writes UNNORMALIZED exp(s-M) as bf16 P, plus 1/rowsum fp32.
__global__ __launch_bounds__(256, 2)
void score_kernel(const float* __restrict__ q, const float* __restrict__ k,
                  unsigned short* __restrict__ P, float* __restrict__ isum) {
    __shared__ float Kt[512 * 16];
    __shared__ float Qt[128 * 16];
    __shared__ float redm[2][128];
    __shared__ float reds[2][128];
    __shared__ unsigned short Pt[2][64][132];
    const int tid = threadIdx.x;
    const int b = blockIdx.y;
    const int t0 = blockIdx.x * 128;
    {
        const float4* ks = (const float4*)(k + (size_t)b * 512 * 16);
        float4* kd = (float4*)Kt;
#pragma unroll
        for (int i = 0; i < 8; i++) kd[i * 256 + tid] = ks[i * 256 + tid];
        const float4* qs = (const float4*)(q + ((size_t)b * 512 + t0) * 16);
        float4* qd = (float4*)Qt;
#pragma unroll
        for (int i = 0; i < 2; i++) qd[i * 256 + tid] = qs[i * 256 + tid];
    }
    __syncthreads();
    const int row = tid & 127;
    const int half = tid >> 7;
    const int sbeg = half * 256;
    const int tglob = t0 + row;
    float qr[16];
#pragma unroll
    for (int j = 0; j < 16; j++) qr[j] = Qt[row * 16 + j];

    float m = -INFINITY;
    for (int s = sbeg; s < sbeg + 256; s++) {
        const float* kk = Kt + s * 16;
        float dot = 0.f;
#pragma unroll
        for (int j = 0; j < 16; j++) dot = fmaf(qr[j], kk[j], dot);
        float sc = (s > tglob) ? NEG_BIG : dot * 4.0f;
        m = fmaxf(m, sc);
    }
    redm[half][row] = m;
    __syncthreads();
    const float M = fmaxf(redm[0][row], redm[1][row]);
    float sum = 0.f;
    for (int ph = 0; ph < 4; ph++) {
        const int c0 = sbeg + ph * 64;
        for (int s = c0; s < c0 + 64; s++) {
            const float* kk = Kt + s * 16;
            float dot = 0.f;
#pragma unroll
            for (int j = 0; j < 16; j++) dot = fmaf(qr[j], kk[j], dot);
            float sc = (s > tglob) ? NEG_BIG : dot * 4.0f;
            float p = __expf(sc - M);
            sum += p;
            Pt[half][s - c0][row] = f2bf(p);
        }
        __syncthreads();
#pragma unroll
        for (int i = 0; i < 8; i++) {
            int li = i * 256 + tid;
            int h = li >> 10;
            int r = (li >> 3) & 127;
            int cg = li & 7;
            union { unsigned short u[8]; uint4 v; } tmp;
#pragma unroll
            for (int j = 0; j < 8; j++) tmp.u[j] = Pt[h][cg * 8 + j][r];
            *(uint4*)(P + ((size_t)(b * 512 + t0 + r)) * 512 + h * 256 + ph * 64 + cg * 8) = tmp.v;
        }
        __syncthreads();
    }
    reds[half][row] = sum;
    __syncthreads();
    if (half == 0) {
        float tot = reds[0][row] + reds[1][row];
        isum[(size_t)b * 512 + tglob] = 1.0f / tot;
    }
}

// ---------------------------------------------------------------------------
// K5b: out[b][t][e] = (P[b] @ vT[b]^T)[t][e] * isum[b][t]   (full K=512)
// XCD swizzle: XCD c owns batches c*8..c*8+7; within a batch, n-tiles
// consecutive for each m-tile (P m-tile + vT batch stay in L2).
__global__ __launch_bounds__(256, 2)
void pv_kernel(const unsigned short* __restrict__ P,
               const unsigned short* __restrict__ vT,
               const float* __restrict__ isum,
               float* __restrict__ out) {
    __shared__ unsigned short As[128 * 32];
    __shared__ unsigned short Bs[128 * 32];
    const int bid = blockIdx.x;
    const int c = bid & 7;
    const int g = bid >> 3;
    const int b = c * 8 + (g >> 5);
    const int rem = g & 31;
    const int m0 = (rem >> 3) * 128;
    const int n0 = (rem & 7) * 128;
    const int tid = threadIdx.x;
    const int lane = tid & 63;
    const int wave = tid >> 6;
    const int wm = (wave & 1) * 64;
    const int wn = (wave >> 1) * 64;
    const int l15 = lane & 15;
    const int quad = lane >> 4;
    const int arow = tid >> 2;
    const int acol = (tid & 3) * 8;
    const unsigned short* Ab = P + (size_t)b * 512 * 512;
    const unsigned short* Bb = vT + (size_t)b * 1024 * 512;
    f32x4 acc[4][4];
#pragma unroll
    for (int i = 0; i < 4; i++)
#pragma unroll
        for (int j = 0; j < 4; j++)
#pragma unroll
            for (int r = 0; r < 4; r++) acc[i][j][r] = 0.f;

    for (int k0 = 0; k0 < 512; k0 += 32) {
        gload_lds16(Ab + (size_t)(m0 + arow) * 512 + k0 + acol, As + tid * 8);
        gload_lds16(Ab + (size_t)(m0 + 64 + arow) * 512 + k0 + acol, As + 2048 + tid * 8);
        gload_lds16(Bb + (size_t)(n0 + arow) * 512 + k0 + acol, Bs + tid * 8);
        gload_lds16(Bb + (size_t)(n0 + 64 + arow) * 512 + k0 + acol, Bs + 2048 + tid * 8);
        __syncthreads();
        bf16x8 af[4], bfr[4];
#pragma unroll
        for (int i = 0; i < 4; i++) {
            af[i]  = *(const bf16x8*)(As + (wm + i * 16 + l15) * 32 + quad * 8);
            bfr[i] = *(const bf16x8*)(Bs + (wn + i * 16 + l15) * 32 + quad * 8);
        }
#pragma unroll
        for (int i = 0; i < 4; i++)
#pragma unroll
            for (int j = 0; j < 4; j++)
                acc[i][j] = __builtin_amdgcn_mfma_f32_16x16x32_bf16(af[i], bfr[j], acc[i][j], 0, 0, 0);
        __syncthreads();
    }
#pragma unroll
    for (int i = 0; i < 4; i++) {
#pragma unroll
        for (int r = 0; r < 4; r++) {
            const int trow = m0 + wm + i * 16 + quad * 4 + r;
            const float sc = isum[(size_t)b * 512 + trow];
#pragma unroll
            for (int j = 0; j < 4; j++) {
                const int ncol = n0 + wn + j * 16 + l15;
                out[((size_t)b * 512 + trow) * 1024 + ncol] = acc[i][j][r] * sc;
            }
        }
    }
}

// ---------------------------------------------------------------------------
extern "C" void kernel_launch(void* const* d_in, const int* in_sizes, int n_in,
                              void* d_out, int out_size, void* d_ws, size_t ws_size,
                              hipStream_t stream) {
    const float* x  = (const float*)d_in[0];
    const void*  pm = d_in[1];
    const float* Wq = (const float*)d_in[2];
    const float* bq = (const float*)d_in[3];
    const float* Wk = (const float*)d_in[4];
    const float* bk = (const float*)d_in[5];
    const float* Wv = (const float*)d_in[6];
    const float* bv = (const float*)d_in[7];
    float* out = (float*)d_out;

    char* ws = (char*)d_ws;
    const size_t MB = 1024 * 1024;
    unsigned short* xbf = (unsigned short*)ws;                 // 64MB (K1->K3)
    unsigned short* Pun = (unsigned short*)ws;                 // 32MB overlay (K5a->K5b, after xbf dead)
    unsigned short* vT  = (unsigned short*)(ws + 64 * MB);     // 64MB
    float* qbuf = (float*)(ws + 128 * MB);                     // 2MB
    float* kbuf = (float*)(ws + 130 * MB);                     // 2MB
    unsigned short* WvT = (unsigned short*)(ws + 132 * MB);    // 2MB
    float* isum = (float*)(ws + 134 * MB);                     // 128KB
    int* flag   = (int*)(ws + 135 * MB);

    detect_mask_kernel<<<1, 256, 0, stream>>>((const unsigned*)pm, flag);
    qk_conv_kernel<<<512, 1024, 0, stream>>>(x, Wq, bq, Wk, bk, pm, flag, xbf, qbuf, kbuf);
    wvt_kernel<<<dim3(32, 32), 256, 0, stream>>>(Wv, WvT);
    vgemm_kernel<<<2048, 256, 0, stream>>>(xbf, WvT, bv, vT);
    score_kernel<<<dim3(4, 64), 256, 0, stream>>>(qbuf, kbuf, Pun, isum);
    pv_kernel<<<2048, 256, 0, stream>>>(Pun, vT, isum, out);
}

// Round 3
// 467.519 us; speedup vs baseline: 1.1766x; 1.0099x over previous
//
#include <hip/hip_runtime.h>
#include <hip/hip_bf16.h>
#include <stdint.h>

#define NEG_BIG (-1e24f)

typedef __attribute__((ext_vector_type(8))) short bf16x8;
typedef __attribute__((ext_vector_type(4))) float f32x4;

#define AS1 __attribute__((address_space(1)))
#define AS3 __attribute__((address_space(3)))

__device__ __forceinline__ void gload_lds16(const void* g, void* l) {
    __builtin_amdgcn_global_load_lds((AS1 unsigned*)g, (AS3 unsigned*)l, 16, 0, 0);
}

__device__ __forceinline__ unsigned short f2bf(float f) {
    union { float f; unsigned u; } v; v.f = f;
    return (unsigned short)((v.u + 0x7FFFu + ((v.u >> 16) & 1u)) >> 16);
}

// ---------------------------------------------------------------------------
// K0: detect padding_mask storage dtype from its bit patterns.
// flag: 0 = int32 {0,1}, 1 = uint8 bytes, 2 = float32 {0.0,1.0}
__global__ void detect_mask_kernel(const unsigned* pm, int* flag) {
    __shared__ int notI, notF;
    if (threadIdx.x == 0) { notI = 0; notF = 0; }
    __syncthreads();
    int li = 0, lf = 0;
    for (int i = threadIdx.x; i < 8192; i += 256) {
        unsigned v = pm[i];
        if (v > 1u) li = 1;
        if (v != 0u && v != 0x3F800000u) lf = 1;
    }
    if (li) atomicOr(&notI, 1);
    if (lf) atomicOr(&notF, 1);
    __syncthreads();
    if (threadIdx.x == 0) *flag = notI ? (notF ? 1 : 2) : 0;
}

// ---------------------------------------------------------------------------
// K1 (v4): 1024-thread blocks (16 waves): 4 output-groups x 4 K-slices.
// In-block split-K + LDS tree-reduce; register prefetch of next chunk.
__global__ __launch_bounds__(1024, 8)
void qk_conv_kernel(const float* __restrict__ x,
                    const float* __restrict__ Wq, const float* __restrict__ bq,
                    const float* __restrict__ Wk, const float* __restrict__ bk,
                    const void* __restrict__ pm, const int* __restrict__ pmflag,
                    unsigned short* __restrict__ xbf,
                    float* __restrict__ qo, float* __restrict__ ko) {
    // union: xs[64*65] staging (16.6KB)  |  red[4][64][33] partials (33.8KB)
    __shared__ float smem[4 * 64 * 33];
    float* xs = smem;
    const int tid = threadIdx.x;
    const int r0 = blockIdx.x * 64;
    const int lane = tid & 63;
    const int wv = __builtin_amdgcn_readfirstlane(tid >> 6);  // 0..15
    const int g = wv & 3;              // 0,1 = q-halves; 2,3 = k-halves
    const int sl = wv >> 2;            // K-slice 0..3 (16 cols of each chunk)
    const int jb = (g & 1) * 8;
    const int d0 = sl * 16;
    const float* __restrict__ W = (g < 2) ? Wq : Wk;

    const int sr = tid >> 4;           // staging row 0..63
    const int sd = (tid & 15) * 4;     // staging col within chunk
    const float* __restrict__ xp = x + (size_t)(r0 + sr) * 1024 + sd;
    unsigned short* __restrict__ xbp = xbf + (size_t)(r0 + sr) * 1024 + sd;

    float acc[8];
#pragma unroll
    for (int j = 0; j < 8; j++) acc[j] = 0.f;

    float4 xv = *(const float4*)xp;    // prefetch chunk 0
    for (int c0 = 0; c0 < 1024; c0 += 64) {
        // ---- stage current chunk into LDS; fused bf16 convert/store
        uint2 pk;
        pk.x = (unsigned)f2bf(xv.x) | ((unsigned)f2bf(xv.y) << 16);
        pk.y = (unsigned)f2bf(xv.z) | ((unsigned)f2bf(xv.w) << 16);
        *(uint2*)(xbp + c0) = pk;
        xs[sr * 65 + sd + 0] = xv.x;
        xs[sr * 65 + sd + 1] = xv.y;
        xs[sr * 65 + sd + 2] = xv.z;
        xs[sr * 65 + sd + 3] = xv.w;
        __syncthreads();
        // issue next chunk's global load now; it flies under the compute
        if (c0 + 64 < 1024) xv = *(const float4*)(xp + c0 + 64);
        // ---- accumulate this wave's 16-col sub-slice
        const float* __restrict__ wrow = W + (size_t)(c0 + d0) * 16 + jb;
        const float* __restrict__ xrow = xs + lane * 65 + d0;
#pragma unroll 4
        for (int dd = 0; dd < 16; dd++) {
            const float xvv = xrow[dd];
            const float* __restrict__ w = wrow + (size_t)dd * 16;
#pragma unroll
            for (int j = 0; j < 8; j++) acc[j] = fmaf(xvv, w[j], acc[j]);
        }
        __syncthreads();
    }

    // ---- cross-slice reduction through LDS (stride 33 -> 2-way free banks)
    float* red = smem;
    const int cb = jb + (g >> 1) * 16;      // col base 0/8/16/24
    {
        float* rr = red + ((size_t)(sl * 64 + lane)) * 33 + cb;
#pragma unroll
        for (int j = 0; j < 8; j++) rr[j] = acc[j];
    }
    __syncthreads();

    // ---- epilogue: each thread finishes one q element + one k element
    const int row = tid >> 4;
    const int c = tid & 15;
    const int grow = r0 + row;
    const float qv = red[(size_t)row * 33 + c]
                   + red[(size_t)(64 + row) * 33 + c]
                   + red[(size_t)(128 + row) * 33 + c]
                   + red[(size_t)(192 + row) * 33 + c] + bq[c];
    qo[(size_t)grow * 16 + c] = qv;
    const int flag = *pmflag;
    bool mk;
    if (flag == 1) mk = ((const unsigned char*)pm)[grow] != 0;
    else           mk = ((const unsigned*)pm)[grow] != 0;
    float kv;
    if (mk) {
        kv = NEG_BIG;
    } else {
        kv = red[(size_t)row * 33 + 16 + c]
           + red[(size_t)(64 + row) * 33 + 16 + c]
           + red[(size_t)(128 + row) * 33 + 16 + c]
           + red[(size_t)(192 + row) * 33 + 16 + c] + bk[c];
    }
    ko[(size_t)grow * 16 + c] = kv;
}

// ---------------------------------------------------------------------------
// K2: WvT[n][k] = bf16(Wv[k][n])  (B-operand layout for MFMA GEMM)
__global__ void wvt_kernel(const float* __restrict__ Wv, unsigned short* __restrict__ WvT) {
    __shared__ float tile[32][33];
    const int k0 = blockIdx.x * 32, n0 = blockIdx.y * 32;
    const int tid = threadIdx.x;
#pragma unroll
    for (int i = 0; i < 4; i++) {
        int idx = i * 256 + tid;
        int r = idx >> 5, c = idx & 31;
        tile[r][c] = Wv[(size_t)(k0 + r) * 1024 + n0 + c];
    }
    __syncthreads();
#pragma unroll
    for (int i = 0; i < 4; i++) {
        int idx = i * 256 + tid;
        int r = idx >> 5, c = idx & 31;
        WvT[(size_t)(n0 + r) * 1024 + k0 + c] = f2bf(tile[c][r]);
    }
}

// ---------------------------------------------------------------------------
// K3 (v2): v = xbf @ WvT + bv, output DIRECTLY transposed: vT[b][e][s].
// T3-minimum double-buffered pipeline: STAGE(t+1) issued BEFORE ds_read+MFMA
// of tile t; ONE __syncthreads per K-step (its vmcnt/lgkm drain lands after
// the MFMAs, so the global->LDS latency hides under compute).
// LDS: dbuf 2x(As 8KB + Bs 8KB) = 32KB, overlaid by 34.8KB epilogue buffer.
__global__ __launch_bounds__(256, 4)
void vgemm_kernel(const unsigned short* __restrict__ A,   // [32768][1024] bf16
                  const unsigned short* __restrict__ Bt,  // [1024][1024] bf16 (n-major)
                  const float* __restrict__ bias,
                  unsigned short* __restrict__ vTg) {     // [64][1024][512] bf16
    __shared__ __align__(16) unsigned short smem[17408];  // dbuf(16384) | vt(128*136)
    const int bid = blockIdx.x;
    const int c = bid & 7;
    const int g = bid >> 3;
    const int mt = c * 32 + (g >> 3);
    const int nt = g & 7;
    const int m0 = mt * 128;
    const int n0 = nt * 128;
    const int tid = threadIdx.x;
    const int lane = tid & 63;
    const int wave = tid >> 6;
    const int wm = (wave & 1) * 64;
    const int wn = (wave >> 1) * 64;
    const int l15 = lane & 15;
    const int quad = lane >> 4;
    const int arow = tid >> 2;
    const int acol = (tid & 3) * 8;
    const unsigned short* __restrict__ Ar0 = A + (size_t)(m0 + arow) * 1024 + acol;
    const unsigned short* __restrict__ Ar1 = A + (size_t)(m0 + 64 + arow) * 1024 + acol;
    const unsigned short* __restrict__ Br0 = Bt + (size_t)(n0 + arow) * 1024 + acol;
    const unsigned short* __restrict__ Br1 = Bt + (size_t)(n0 + 64 + arow) * 1024 + acol;
    f32x4 acc[4][4];
#pragma unroll
    for (int i = 0; i < 4; i++)
#pragma unroll
        for (int j = 0; j < 4; j++)
#pragma unroll
            for (int r = 0; r < 4; r++) acc[i][j][r] = 0.f;

    // prologue: stage tile 0 into buffer 0
    {
        unsigned short* As = smem;
        unsigned short* Bs = smem + 4096;
        gload_lds16(Ar0, As + tid * 8);
        gload_lds16(Ar1, As + 2048 + tid * 8);
        gload_lds16(Br0, Bs + tid * 8);
        gload_lds16(Br1, Bs + 2048 + tid * 8);
    }
    __syncthreads();
    int cur = 0;
    for (int t = 0; t < 32; t++) {
        // stage next tile into the other buffer (flies under this tile's MFMA)
        if (t + 1 < 32) {
            const int kn = (t + 1) * 32;
            unsigned short* As = smem + (cur ^ 1) * 8192;
            unsigned short* Bs = As + 4096;
            gload_lds16(Ar0 + kn, As + tid * 8);
            gload_lds16(Ar1 + kn, As + 2048 + tid * 8);
            gload_lds16(Br0 + kn, Bs + tid * 8);
            gload_lds16(Br1 + kn, Bs + 2048 + tid * 8);
        }
        const unsigned short* As = smem + cur * 8192;
        const unsigned short* Bs = As + 4096;
        bf16x8 af[4], bfr[4];
#pragma unroll
        for (int i = 0; i < 4; i++) {
            af[i]  = *(const bf16x8*)(As + (wm + i * 16 + l15) * 32 + quad * 8);
            bfr[i] = *(const bf16x8*)(Bs + (wn + i * 16 + l15) * 32 + quad * 8);
        }
#pragma unroll
        for (int i = 0; i < 4; i++)
#pragma unroll
            for (int j = 0; j < 4; j++)
                acc[i][j] = __builtin_amdgcn_mfma_f32_16x16x32_bf16(af[i], bfr[j], acc[i][j], 0, 0, 0);
        __syncthreads();   // drains vmcnt (stage done) + lgkm (reads done)
        cur ^= 1;
    }
    // epilogue: bias + transpose through LDS, store vT coalesced
    unsigned short* vt = smem;  // reuse (safe: barrier above after last reads)
#pragma unroll
    for (int j = 0; j < 4; j++) {
        const int e_local = wn + j * 16 + l15;
        const float bb = bias[n0 + e_local];
#pragma unroll
        for (int i = 0; i < 4; i++) {
            const int s_base = wm + i * 16 + quad * 4;
            unsigned short h0 = f2bf(acc[i][j][0] + bb);
            unsigned short h1 = f2bf(acc[i][j][1] + bb);
            unsigned short h2 = f2bf(acc[i][j][2] + bb);
            unsigned short h3 = f2bf(acc[i][j][3] + bb);
            uint2 u;
            u.x = (unsigned)h0 | ((unsigned)h1 << 16);
            u.y = (unsigned)h2 | ((unsigned)h3 << 16);
            *(uint2*)(vt + e_local * 136 + s_base) = u;
        }
    }
    __syncthreads();
    const int b = m0 >> 9;
    const int sbase = m0 & 511;
#pragma unroll
    for (int p = 0; p < 8; p++) {
        const int idx = p * 256 + tid;
        const int e = idx >> 4;
        const int s8 = (idx & 15) * 8;
        uint4 val = *(const uint4*)(vt + e * 136 + s8);
        *(uint4*)(vTg + ((size_t)b * 1024 + n0 + e) * 512 + sbase + s8) = val;
    }
}

// ---------------------------------------------------------------------------
// K5a: fp32 scores (q.k*4, causal -1e24) + 2-pass softmax.
// Writes UNNORMALIZED exp(s-M) as bf16 P, plus 1/rowsum fp32.
__global__ __launch_bounds__(256, 2)
void score_kernel(const float* __restrict__ q, const float* __restrict__ k,
                  unsigned short* __restrict__ P, float* __restrict__ isum) {
    __shared__ float Kt[512 * 16];
    __shared__ float Qt[128 * 16];
    __shared__ float redm[2][128];
    __shared__ float reds[2][128];
    __shared__ unsigned short Pt[2][64][132];
    const int tid = threadIdx.x;
    const int b = blockIdx.y;
    const int t0 = blockIdx.x * 128;
    {
        const float4* ks = (const float4*)(k + (size_t)b * 512 * 16);
        float4* kd = (float4*)Kt;
#pragma unroll
        for (int i = 0; i < 8; i++) kd[i * 256 + tid] = ks[i * 256 + tid];
        const float4* qs = (const float4*)(q + ((size_t)b * 512 + t0) * 16);
        float4* qd = (float4*)Qt;
#pragma unroll
        for (int i = 0; i < 2; i++) qd[i * 256 + tid] = qs[i * 256 + tid];
    }
    __syncthreads();
    const int row = tid & 127;
    const int half = tid >> 7;
    const int sbeg = half * 256;
    const int tglob = t0 + row;
    float qr[16];
#pragma unroll
    for (int j = 0; j < 16; j++) qr[j] = Qt[row * 16 + j];

    float m = -INFINITY;
    for (int s = sbeg; s < sbeg + 256; s++) {
        const float* kk = Kt + s * 16;
        float dot = 0.f;
#pragma unroll
        for (int j = 0; j < 16; j++) dot = fmaf(qr[j], kk[j], dot);
        float sc = (s > tglob) ? NEG_BIG : dot * 4.0f;
        m = fmaxf(m, sc);
    }
    redm[half][row] = m;
    __syncthreads();
    const float M = fmaxf(redm[0][row], redm[1][row]);
    float sum = 0.f;
    for (int ph = 0; ph < 4; ph++) {
        const int c0 = sbeg + ph * 64;
        for (int s = c0; s < c0 + 64; s++) {
            const float* kk = Kt + s * 16;
            float dot = 0.f;
#pragma unroll
            for (int j = 0; j < 16; j++) dot = fmaf(qr[j], kk[j], dot);
            float sc = (s > tglob) ? NEG_BIG : dot * 4.0f;
            float p = __expf(sc - M);
            sum += p;
            Pt[half][s - c0][row] = f2bf(p);
        }
        __syncthreads();
#pragma unroll
        for (int i = 0; i < 8; i++) {
            int li = i * 256 + tid;
            int h = li >> 10;
            int r = (li >> 3) & 127;
            int cg = li & 7;
            union { unsigned short u[8]; uint4 v; } tmp;
#pragma unroll
            for (int j = 0; j < 8; j++) tmp.u[j] = Pt[h][cg * 8 + j][r];
            *(uint4*)(P + ((size_t)(b * 512 + t0 + r)) * 512 + h * 256 + ph * 64 + cg * 8) = tmp.v;
        }
        __syncthreads();
    }
    reds[half][row] = sum;
    __syncthreads();
    if (half == 0) {
        float tot = reds[0][row] + reds[1][row];
        isum[(size_t)b * 512 + tglob] = 1.0f / tot;
    }
}

// ---------------------------------------------------------------------------
// K5b (v2): out[b][t][e] = (P[b] @ vT[b]^T)[t][e] * isum[b][t]
// Same T3-minimum double-buffered pipeline as K3.
__global__ __launch_bounds__(256, 4)
void pv_kernel(const unsigned short* __restrict__ P,
               const unsigned short* __restrict__ vT,
               const float* __restrict__ isum,
               float* __restrict__ out) {
    __shared__ __align__(16) unsigned short smem[16384];  // dbuf 2x(As+Bs)
    const int bid = blockIdx.x;
    const int c = bid & 7;
    const int g = bid >> 3;
    const int b = c * 8 + (g >> 5);
    const int rem = g & 31;
    const int m0 = (rem >> 3) * 128;
    const int n0 = (rem & 7) * 128;
    const int tid = threadIdx.x;
    const int lane = tid & 63;
    const int wave = tid >> 6;
    const int wm = (wave & 1) * 64;
    const int wn = (wave >> 1) * 64;
    const int l15 = lane & 15;
    const int quad = lane >> 4;
    const int arow = tid >> 2;
    const int acol = (tid & 3) * 8;
    const unsigned short* __restrict__ Ar0 = P + (size_t)b * 512 * 512 + (size_t)(m0 + arow) * 512 + acol;
    const unsigned short* __restrict__ Ar1 = Ar0 + (size_t)64 * 512;
    const unsigned short* __restrict__ Br0 = vT + (size_t)b * 1024 * 512 + (size_t)(n0 + arow) * 512 + acol;
    const unsigned short* __restrict__ Br1 = Br0 + (size_t)64 * 512;
    f32x4 acc[4][4];
#pragma unroll
    for (int i = 0; i < 4; i++)
#pragma unroll
        for (int j = 0; j < 4; j++)
#pragma unroll
            for (int r = 0; r < 4; r++) acc[i][j][r] = 0.f;

    {
        unsigned short* As = smem;
        unsigned short* Bs = smem + 4096;
        gload_lds16(Ar0, As + tid * 8);
        gload_lds16(Ar1, As + 2048 + tid * 8);
        gload_lds16(Br0, Bs + tid * 8);
        gload_lds16(Br1, Bs + 2048 + tid * 8);
    }
    __syncthreads();
    int cur = 0;
    for (int t = 0; t < 16; t++) {
        if (t + 1 < 16) {
            const int kn = (t + 1) * 32;
            unsigned short* As = smem + (cur ^ 1) * 8192;
            unsigned short* Bs = As + 4096;
            gload_lds16(Ar0 + kn, As + tid * 8);
            gload_lds16(Ar1 + kn, As + 2048 + tid * 8);
            gload_lds16(Br0 + kn, Bs + tid * 8);
            gload_lds16(Br1 + kn, Bs + 2048 + tid * 8);
        }
        const unsigned short* As = smem + cur * 8192;
        const unsigned short* Bs = As + 4096;
        bf16x8 af[4], bfr[4];
#pragma unroll
        for (int i = 0; i < 4; i++) {
            af[i]  = *(const bf16x8*)(As + (wm + i * 16 + l15) * 32 + quad * 8);
            bfr[i] = *(const bf16x8*)(Bs + (wn + i * 16 + l15) * 32 + quad * 8);
        }
#pragma unroll
        for (int i = 0; i < 4; i++)
#pragma unroll
            for (int j = 0; j < 4; j++)
                acc[i][j] = __builtin_amdgcn_mfma_f32_16x16x32_bf16(af[i], bfr[j], acc[i][j], 0, 0, 0);
        __syncthreads();
        cur ^= 1;
    }
#pragma unroll
    for (int i = 0; i < 4; i++) {
#pragma unroll
        for (int r = 0; r < 4; r++) {
            const int trow = m0 + wm + i * 16 + quad * 4 + r;
            const float sc = isum[(size_t)b * 512 + trow];
#pragma unroll
            for (int j = 0; j < 4; j++) {
                const int ncol = n0 + wn + j * 16 + l15;
                out[((size_t)b * 512 + trow) * 1024 + ncol] = acc[i][j][r] * sc;
            }
        }
    }
}

// ---------------------------------------------------------------------------
extern "C" void kernel_launch(void* const* d_in, const int* in_sizes, int n_in,
                              void* d_out, int out_size, void* d_ws, size_t ws_size,
                              hipStream_t stream) {
    const float* x  = (const float*)d_in[0];
    const void*  pm = d_in[1];
    const float* Wq = (const float*)d_in[2];
    const float* bq = (const float*)d_in[3];
    const float* Wk = (const float*)d_in[4];
    const float* bk = (const float*)d_in[5];
    const float* Wv = (const float*)d_in[6];
    const float* bv = (const float*)d_in[7];
    float* out = (float*)d_out;

    char* ws = (char*)d_ws;
    const size_t MB = 1024 * 1024;
    unsigned short* xbf = (unsigned short*)ws;                 // 64MB (K1->K3)
    unsigned short* Pun = (unsigned short*)ws;                 // 32MB overlay (K5a->K5b, after xbf dead)
    unsigned short* vT  = (unsigned short*)(ws + 64 * MB);     // 64MB
    float* qbuf = (float*)(ws + 128 * MB);                     // 2MB
    float* kbuf = (float*)(ws + 130 * MB);                     // 2MB
    unsigned short* WvT = (unsigned short*)(ws + 132 * MB);    // 2MB
    float* isum = (float*)(ws + 134 * MB);                     // 128KB
    int* flag   = (int*)(ws + 135 * MB);

    detect_mask_kernel<<<1, 256, 0, stream>>>((const unsigned*)pm, flag);
    qk_conv_kernel<<<512, 1024, 0, stream>>>(x, Wq, bq, Wk, bk, pm, flag, xbf, qbuf, kbuf);
    wvt_kernel<<<dim3(32, 32), 256, 0, stream>>>(Wv, WvT);
    vgemm_kernel<<<2048, 256, 0, stream>>>(xbf, WvT, bv, vT);
    score_kernel<<<dim3(4, 64), 256, 0, stream>>>(qbuf, kbuf, Pun, isum);
    pv_kernel<<<2048, 256, 0, stream>>>(Pun, vT, isum, out);
}

// Round 4
// 458.495 us; speedup vs baseline: 1.1997x; 1.0197x over previous
//
#include <hip/hip_runtime.h>
#include <hip/hip_bf16.h>
#include <stdint.h>

#define NEG_BIG (-1e24f)

typedef __attribute__((ext_vector_type(8))) short bf16x8;
typedef __attribute__((ext_vector_type(4))) float f32x4;

#define AS1 __attribute__((address_space(1)))
#define AS3 __attribute__((address_space(3)))

__device__ __forceinline__ void gload_lds16(const void* g, void* l) {
    __builtin_amdgcn_global_load_lds((AS1 unsigned*)g, (AS3 unsigned*)l, 16, 0, 0);
}

__device__ __forceinline__ unsigned short f2bf(float f) {
    union { float f; unsigned u; } v; v.f = f;
    return (unsigned short)((v.u + 0x7FFFu + ((v.u >> 16) & 1u)) >> 16);
}

// raw barrier: drain LDS ops only (NOT vmcnt -> in-flight global prefetch survives)
__device__ __forceinline__ void lds_barrier() {
    asm volatile("s_waitcnt lgkmcnt(0)" ::: "memory");
    __builtin_amdgcn_s_barrier();
    asm volatile("" ::: "memory");
}

// ---------------------------------------------------------------------------
// K0: detect padding_mask storage dtype from its bit patterns.
// flag: 0 = int32 {0,1}, 1 = uint8 bytes, 2 = float32 {0.0,1.0}
__global__ void detect_mask_kernel(const unsigned* pm, int* flag) {
    __shared__ int notI, notF;
    if (threadIdx.x == 0) { notI = 0; notF = 0; }
    __syncthreads();
    int li = 0, lf = 0;
    for (int i = threadIdx.x; i < 8192; i += 256) {
        unsigned v = pm[i];
        if (v > 1u) li = 1;
        if (v != 0u && v != 0x3F800000u) lf = 1;
    }
    if (li) atomicOr(&notI, 1);
    if (lf) atomicOr(&notF, 1);
    __syncthreads();
    if (threadIdx.x == 0) *flag = notI ? (notF ? 1 : 2) : 0;
}

// ---------------------------------------------------------------------------
// K1 (v5): 1024-thread blocks, 16 waves = 4 output-groups x 4 K-slices.
// DOUBLE-BUFFERED LDS x-staging with ONE raw-barrier per chunk and no vmcnt
// drains in the loop: the next chunk's float4 stays in flight across the
// barrier (true async pipeline). x-reads paired (ds_read2_b32 fusion), full
// unroll for MLP. Exact fp32 q/k; epilogue identical to v4 (verified).
__global__ __launch_bounds__(1024, 8)
void qk_conv_kernel(const float* __restrict__ x,
                    const float* __restrict__ Wq, const float* __restrict__ bq,
                    const float* __restrict__ Wk, const float* __restrict__ bk,
                    const void* __restrict__ pm, const int* __restrict__ pmflag,
                    unsigned short* __restrict__ xbf,
                    float* __restrict__ qo, float* __restrict__ ko) {
    // union: 2 x-buffers [64*65] (33.3KB)  |  red[4][64][33] partials (33.8KB)
    __shared__ float smem[4 * 64 * 33];
    const int tid = threadIdx.x;
    const int r0 = blockIdx.x * 64;
    const int lane = tid & 63;
    const int wv = __builtin_amdgcn_readfirstlane(tid >> 6);  // 0..15
    const int g = wv & 3;              // 0,1 = q-halves; 2,3 = k-halves
    const int sl = wv >> 2;            // K-slice 0..3 (16 cols of each chunk)
    const int jb = (g & 1) * 8;
    const int d0 = sl * 16;
    const float* __restrict__ W = (g < 2) ? Wq : Wk;

    const int sr = tid >> 4;           // staging row 0..63
    const int sd = (tid & 15) * 4;     // staging col within chunk
    const float* __restrict__ xp = x + (size_t)(r0 + sr) * 1024 + sd;
    unsigned short* __restrict__ xbp = xbf + (size_t)(r0 + sr) * 1024 + sd;

    float acc[8];
#pragma unroll
    for (int j = 0; j < 8; j++) acc[j] = 0.f;

    // ---- prologue: stage chunk 0 into buf0, start chunk-1 load
    float4 xv = *(const float4*)xp;                    // chunk 0
    {
        uint2 pk;
        pk.x = (unsigned)f2bf(xv.x) | ((unsigned)f2bf(xv.y) << 16);
        pk.y = (unsigned)f2bf(xv.z) | ((unsigned)f2bf(xv.w) << 16);
        *(uint2*)xbp = pk;
        float* b0 = smem;                              // buf0
        b0[sr * 65 + sd + 0] = xv.x;
        b0[sr * 65 + sd + 1] = xv.y;
        b0[sr * 65 + sd + 2] = xv.z;
        b0[sr * 65 + sd + 3] = xv.w;
    }
    xv = *(const float4*)(xp + 64);                    // chunk 1 (in flight)
    lds_barrier();

    for (int t = 0; t < 16; t++) {
        // ---- stage chunk t+1 into buf[(t+1)&1] while computing chunk t
        if (t + 1 < 16) {
            uint2 pk;
            pk.x = (unsigned)f2bf(xv.x) | ((unsigned)f2bf(xv.y) << 16);
            pk.y = (unsigned)f2bf(xv.z) | ((unsigned)f2bf(xv.w) << 16);
            *(uint2*)(xbp + (t + 1) * 64) = pk;
            float* bw = smem + ((t + 1) & 1) * (64 * 65);
            bw[sr * 65 + sd + 0] = xv.x;
            bw[sr * 65 + sd + 1] = xv.y;
            bw[sr * 65 + sd + 2] = xv.z;
            bw[sr * 65 + sd + 3] = xv.w;
            if (t + 2 < 16) xv = *(const float4*)(xp + (t + 2) * 64);  // stays in flight
        }
        // ---- compute chunk t from buf[t&1]
        const float* __restrict__ xrow = smem + (t & 1) * (64 * 65) + lane * 65 + d0;
        const float* __restrict__ wrow = W + (size_t)(t * 64 + d0) * 16 + jb;
#pragma unroll
        for (int dd = 0; dd < 16; dd += 2) {
            const float x0 = xrow[dd];
            const float x1 = xrow[dd + 1];
            const float* __restrict__ w0 = wrow + dd * 16;
#pragma unroll
            for (int j = 0; j < 8; j++) acc[j] = fmaf(x0, w0[j], acc[j]);
#pragma unroll
            for (int j = 0; j < 8; j++) acc[j] = fmaf(x1, w0[16 + j], acc[j]);
        }
        lds_barrier();   // all waves done reading buf[t&1]; writes of t+1 committed
    }

    // ---- cross-slice reduction through LDS (stride 33 -> 2-way free banks)
    float* red = smem;
    const int cb = jb + (g >> 1) * 16;      // col base 0/8/16/24
    {
        float* rr = red + ((size_t)(sl * 64 + lane)) * 33 + cb;
#pragma unroll
        for (int j = 0; j < 8; j++) rr[j] = acc[j];
    }
    __syncthreads();

    // ---- epilogue: each thread finishes one q element + one k element
    const int row = tid >> 4;
    const int c = tid & 15;
    const int grow = r0 + row;
    const float qv = red[(size_t)row * 33 + c]
                   + red[(size_t)(64 + row) * 33 + c]
                   + red[(size_t)(128 + row) * 33 + c]
                   + red[(size_t)(192 + row) * 33 + c] + bq[c];
    qo[(size_t)grow * 16 + c] = qv;
    const int flag = *pmflag;
    bool mk;
    if (flag == 1) mk = ((const unsigned char*)pm)[grow] != 0;
    else           mk = ((const unsigned*)pm)[grow] != 0;
    float kv;
    if (mk) {
        kv = NEG_BIG;
    } else {
        kv = red[(size_t)row * 33 + 16 + c]
           + red[(size_t)(64 + row) * 33 + 16 + c]
           + red[(size_t)(128 + row) * 33 + 16 + c]
           + red[(size_t)(192 + row) * 33 + 16 + c] + bk[c];
    }
    ko[(size_t)grow * 16 + c] = kv;
}

// ---------------------------------------------------------------------------
// K2: WvT[n][k] = bf16(Wv[k][n])  (B-operand layout for MFMA GEMM)
__global__ void wvt_kernel(const float* __restrict__ Wv, unsigned short* __restrict__ WvT) {
    __shared__ float tile[32][33];
    const int k0 = blockIdx.x * 32, n0 = blockIdx.y * 32;
    const int tid = threadIdx.x;
#pragma unroll
    for (int i = 0; i < 4; i++) {
        int idx = i * 256 + tid;
        int r = idx >> 5, c = idx & 31;
        tile[r][c] = Wv[(size_t)(k0 + r) * 1024 + n0 + c];
    }
    __syncthreads();
#pragma unroll
    for (int i = 0; i < 4; i++) {
        int idx = i * 256 + tid;
        int r = idx >> 5, c = idx & 31;
        WvT[(size_t)(n0 + r) * 1024 + k0 + c] = f2bf(tile[c][r]);
    }
}

// ---------------------------------------------------------------------------
// K3 (v2): v = xbf @ WvT + bv, output DIRECTLY transposed: vT[b][e][s].
// T3-minimum double-buffered pipeline: STAGE(t+1) issued BEFORE ds_read+MFMA
// of tile t; ONE __syncthreads per K-step.
__global__ __launch_bounds__(256, 4)
void vgemm_kernel(const unsigned short* __restrict__ A,   // [32768][1024] bf16
                  const unsigned short* __restrict__ Bt,  // [1024][1024] bf16 (n-major)
                  const float* __restrict__ bias,
                  unsigned short* __restrict__ vTg) {     // [64][1024][512] bf16
    __shared__ __align__(16) unsigned short smem[17408];  // dbuf(16384) | vt(128*136)
    const int bid = blockIdx.x;
    const int c = bid & 7;
    const int g = bid >> 3;
    const int mt = c * 32 + (g >> 3);
    const int nt = g & 7;
    const int m0 = mt * 128;
    const int n0 = nt * 128;
    const int tid = threadIdx.x;
    const int lane = tid & 63;
    const int wave = tid >> 6;
    const int wm = (wave & 1) * 64;
    const int wn = (wave >> 1) * 64;
    const int l15 = lane & 15;
    const int quad = lane >> 4;
    const int arow = tid >> 2;
    const int acol = (tid & 3) * 8;
    const unsigned short* __restrict__ Ar0 = A + (size_t)(m0 + arow) * 1024 + acol;
    const unsigned short* __restrict__ Ar1 = A + (size_t)(m0 + 64 + arow) * 1024 + acol;
    const unsigned short* __restrict__ Br0 = Bt + (size_t)(n0 + arow) * 1024 + acol;
    const unsigned short* __restrict__ Br1 = Bt + (size_t)(n0 + 64 + arow) * 1024 + acol;
    f32x4 acc[4][4];
#pragma unroll
    for (int i = 0; i < 4; i++)
#pragma unroll
        for (int j = 0; j < 4; j++)
#pragma unroll
            for (int r = 0; r < 4; r++) acc[i][j][r] = 0.f;

    // prologue: stage tile 0 into buffer 0
    {
        unsigned short* As = smem;
        unsigned short* Bs = smem + 4096;
        gload_lds16(Ar0, As + tid * 8);
        gload_lds16(Ar1, As + 2048 + tid * 8);
        gload_lds16(Br0, Bs + tid * 8);
        gload_lds16(Br1, Bs + 2048 + tid * 8);
    }
    __syncthreads();
    int cur = 0;
    for (int t = 0; t < 32; t++) {
        if (t + 1 < 32) {
            const int kn = (t + 1) * 32;
            unsigned short* As = smem + (cur ^ 1) * 8192;
            unsigned short* Bs = As + 4096;
            gload_lds16(Ar0 + kn, As + tid * 8);
            gload_lds16(Ar1 + kn, As + 2048 + tid * 8);
            gload_lds16(Br0 + kn, Bs + tid * 8);
            gload_lds16(Br1 + kn, Bs + 2048 + tid * 8);
        }
        const unsigned short* As = smem + cur * 8192;
        const unsigned short* Bs = As + 4096;
        bf16x8 af[4], bfr[4];
#pragma unroll
        for (int i = 0; i < 4; i++) {
            af[i]  = *(const bf16x8*)(As + (wm + i * 16 + l15) * 32 + quad * 8);
            bfr[i] = *(const bf16x8*)(Bs + (wn + i * 16 + l15) * 32 + quad * 8);
        }
#pragma unroll
        for (int i = 0; i < 4; i++)
#pragma unroll
            for (int j = 0; j < 4; j++)
                acc[i][j] = __builtin_amdgcn_mfma_f32_16x16x32_bf16(af[i], bfr[j], acc[i][j], 0, 0, 0);
        __syncthreads();   // drains vmcnt (stage done) + lgkm (reads done)
        cur ^= 1;
    }
    // epilogue: bias + transpose through LDS, store vT coalesced
    unsigned short* vt = smem;  // reuse (safe: barrier above after last reads)
#pragma unroll
    for (int j = 0; j < 4; j++) {
        const int e_local = wn + j * 16 + l15;
        const float bb = bias[n0 + e_local];
#pragma unroll
        for (int i = 0; i < 4; i++) {
            const int s_base = wm + i * 16 + quad * 4;
            unsigned short h0 = f2bf(acc[i][j][0] + bb);
            unsigned short h1 = f2bf(acc[i][j][1] + bb);
            unsigned short h2 = f2bf(acc[i][j][2] + bb);
            unsigned short h3 = f2bf(acc[i][j][3] + bb);
            uint2 u;
            u.x = (unsigned)h0 | ((unsigned)h1 << 16);
            u.y = (unsigned)h2 | ((unsigned)h3 << 16);
            *(uint2*)(vt + e_local * 136 + s_base) = u;
        }
    }
    __syncthreads();
    const int b = m0 >> 9;
    const int sbase = m0 & 511;
#pragma unroll
    for (int p = 0; p < 8; p++) {
        const int idx = p * 256 + tid;
        const int e = idx >> 4;
        const int s8 = (idx & 15) * 8;
        uint4 val = *(const uint4*)(vt + e * 136 + s8);
        *(uint4*)(vTg + ((size_t)b * 1024 + n0 + e) * 512 + sbase + s8) = val;
    }
}

// ---------------------------------------------------------------------------
// K5a: fp32 scores (q.k*4, causal -1e24) + 2-pass softmax.
// Writes UNNORMALIZED exp(s-M) as bf16 P, plus 1/rowsum fp32.
__global__ __launch_bounds__(256, 2)
void score_kernel(const float* __restrict__ q, const float* __restrict__ k,
                  unsigned short* __restrict__ P, float* __restrict__ isum) {
    __shared__ float Kt[512 * 16];
    __shared__ float Qt[128 * 16];
    __shared__ float redm[2][128];
    __shared__ float reds[2][128];
    __shared__ unsigned short Pt[2][64][132];
    const int tid = threadIdx.x;
    const int b = blockIdx.y;
    const int t0 = blockIdx.x * 128;
    {
        const float4* ks = (const float4*)(k + (size_t)b * 512 * 16);
        float4* kd = (float4*)Kt;
#pragma unroll
        for (int i = 0; i < 8; i++) kd[i * 256 + tid] = ks[i * 256 + tid];
        const float4* qs = (const float4*)(q + ((size_t)b * 512 + t0) * 16);
        float4* qd = (float4*)Qt;
#pragma unroll
        for (int i = 0; i < 2; i++) qd[i * 256 + tid] = qs[i * 256 + tid];
    }
    __syncthreads();
    const int row = tid & 127;
    const int half = tid >> 7;
    const int sbeg = half * 256;
    const int tglob = t0 + row;
    float qr[16];
#pragma unroll
    for (int j = 0; j < 16; j++) qr[j] = Qt[row * 16 + j];

    float m = -INFINITY;
    for (int s = sbeg; s < sbeg + 256; s++) {
        const float* kk = Kt + s * 16;
        float dot = 0.f;
#pragma unroll
        for (int j = 0; j < 16; j++) dot = fmaf(qr[j], kk[j], dot);
        float sc = (s > tglob) ? NEG_BIG : dot * 4.0f;
        m = fmaxf(m, sc);
    }
    redm[half][row] = m;
    __syncthreads();
    const float M = fmaxf(redm[0][row], redm[1][row]);
    float sum = 0.f;
    for (int ph = 0; ph < 4; ph++) {
        const int c0 = sbeg + ph * 64;
        for (int s = c0; s < c0 + 64; s++) {
            const float* kk = Kt + s * 16;
            float dot = 0.f;
#pragma unroll
            for (int j = 0; j < 16; j++) dot = fmaf(qr[j], kk[j], dot);
            float sc = (s > tglob) ? NEG_BIG : dot * 4.0f;
            float p = __expf(sc - M);
            sum += p;
            Pt[half][s - c0][row] = f2bf(p);
        }
        __syncthreads();
#pragma unroll
        for (int i = 0; i < 8; i++) {
            int li = i * 256 + tid;
            int h = li >> 10;
            int r = (li >> 3) & 127;
            int cg = li & 7;
            union { unsigned short u[8]; uint4 v; } tmp;
#pragma unroll
            for (int j = 0; j < 8; j++) tmp.u[j] = Pt[h][cg * 8 + j][r];
            *(uint4*)(P + ((size_t)(b * 512 + t0 + r)) * 512 + h * 256 + ph * 64 + cg * 8) = tmp.v;
        }
        __syncthreads();
    }
    reds[half][row] = sum;
    __syncthreads();
    if (half == 0) {
        float tot = reds[0][row] + reds[1][row];
        isum[(size_t)b * 512 + tglob] = 1.0f / tot;
    }
}

// ---------------------------------------------------------------------------
// K5b (v2): out[b][t][e] = (P[b] @ vT[b]^T)[t][e] * isum[b][t]
// Same T3-minimum double-buffered pipeline as K3.
__global__ __launch_bounds__(256, 4)
void pv_kernel(const unsigned short* __restrict__ P,
               const unsigned short* __restrict__ vT,
               const float* __restrict__ isum,
               float* __restrict__ out) {
    __shared__ __align__(16) unsigned short smem[16384];  // dbuf 2x(As+Bs)
    const int bid = blockIdx.x;
    const int c = bid & 7;
    const int g = bid >> 3;
    const int b = c * 8 + (g >> 5);
    const int rem = g & 31;
    const int m0 = (rem >> 3) * 128;
    const int n0 = (rem & 7) * 128;
    const int tid = threadIdx.x;
    const int lane = tid & 63;
    const int wave = tid >> 6;
    const int wm = (wave & 1) * 64;
    const int wn = (wave >> 1) * 64;
    const int l15 = lane & 15;
    const int quad = lane >> 4;
    const int arow = tid >> 2;
    const int acol = (tid & 3) * 8;
    const unsigned short* __restrict__ Ar0 = P + (size_t)b * 512 * 512 + (size_t)(m0 + arow) * 512 + acol;
    const unsigned short* __restrict__ Ar1 = Ar0 + (size_t)64 * 512;
    const unsigned short* __restrict__ Br0 = vT + (size_t)b * 1024 * 512 + (size_t)(n0 + arow) * 512 + acol;
    const unsigned short* __restrict__ Br1 = Br0 + (size_t)64 * 512;
    f32x4 acc[4][4];
#pragma unroll
    for (int i = 0; i < 4; i++)
#pragma unroll
        for (int j = 0; j < 4; j++)
#pragma unroll
            for (int r = 0; r < 4; r++) acc[i][j][r] = 0.f;

    {
        unsigned short* As = smem;
        unsigned short* Bs = smem + 4096;
        gload_lds16(Ar0, As + tid * 8);
        gload_lds16(Ar1, As + 2048 + tid * 8);
        gload_lds16(Br0, Bs + tid * 8);
        gload_lds16(Br1, Bs + 2048 + tid * 8);
    }
    __syncthreads();
    int cur = 0;
    for (int t = 0; t < 16; t++) {
        if (t + 1 < 16) {
            const int kn = (t + 1) * 32;
            unsigned short* As = smem + (cur ^ 1) * 8192;
            unsigned short* Bs = As + 4096;
            gload_lds16(Ar0 + kn, As + tid * 8);
            gload_lds16(Ar1 + kn, As + 2048 + tid * 8);
            gload_lds16(Br0 + kn, Bs + tid * 8);
            gload_lds16(Br1 + kn, Bs + 2048 + tid * 8);
        }
        const unsigned short* As = smem + cur * 8192;
        const unsigned short* Bs = As + 4096;
        bf16x8 af[4], bfr[4];
#pragma unroll
        for (int i = 0; i < 4; i++) {
            af[i]  = *(const bf16x8*)(As + (wm + i * 16 + l15) * 32 + quad * 8);
            bfr[i] = *(const bf16x8*)(Bs + (wn + i * 16 + l15) * 32 + quad * 8);
        }
#pragma unroll
        for (int i = 0; i < 4; i++)
#pragma unroll
            for (int j = 0; j < 4; j++)
                acc[i][j] = __builtin_amdgcn_mfma_f32_16x16x32_bf16(af[i], bfr[j], acc[i][j], 0, 0, 0);
        __syncthreads();
        cur ^= 1;
    }
#pragma unroll
    for (int i = 0; i < 4; i++) {
#pragma unroll
        for (int r = 0; r < 4; r++) {
            const int trow = m0 + wm + i * 16 + quad * 4 + r;
            const float sc = isum[(size_t)b * 512 + trow];
#pragma unroll
            for (int j = 0; j < 4; j++) {
                const int ncol = n0 + wn + j * 16 + l15;
                out[((size_t)b * 512 + trow) * 1024 + ncol] = acc[i][j][r] * sc;
            }
        }
    }
}

// ---------------------------------------------------------------------------
extern "C" void kernel_launch(void* const* d_in, const int* in_sizes, int n_in,
                              void* d_out, int out_size, void* d_ws, size_t ws_size,
                              hipStream_t stream) {
    const float* x  = (const float*)d_in[0];
    const void*  pm = d_in[1];
    const float* Wq = (const float*)d_in[2];
    const float* bq = (const float*)d_in[3];
    const float* Wk = (const float*)d_in[4];
    const float* bk = (const float*)d_in[5];
    const float* Wv = (const float*)d_in[6];
    const float* bv = (const float*)d_in[7];
    float* out = (float*)d_out;

    char* ws = (char*)d_ws;
    const size_t MB = 1024 * 1024;
    unsigned short* xbf = (unsigned short*)ws;                 // 64MB (K1->K3)
    unsigned short* Pun = (unsigned short*)ws;                 // 32MB overlay (K5a->K5b, after xbf dead)
    unsigned short* vT  = (unsigned short*)(ws + 64 * MB);     // 64MB
    float* qbuf = (float*)(ws + 128 * MB);                     // 2MB
    float* kbuf = (float*)(ws + 130 * MB);                     // 2MB
    unsigned short* WvT = (unsigned short*)(ws + 132 * MB);    // 2MB
    float* isum = (float*)(ws + 134 * MB);                     // 128KB
    int* flag   = (int*)(ws + 135 * MB);

    detect_mask_kernel<<<1, 256, 0, stream>>>((const unsigned*)pm, flag);
    qk_conv_kernel<<<512, 1024, 0, stream>>>(x, Wq, bq, Wk, bk, pm, flag, xbf, qbuf, kbuf);
    wvt_kernel<<<dim3(32, 32), 256, 0, stream>>>(Wv, WvT);
    vgemm_kernel<<<2048, 256, 0, stream>>>(xbf, WvT, bv, vT);
    score_kernel<<<dim3(4, 64), 256, 0, stream>>>(qbuf, kbuf, Pun, isum);
    pv_kernel<<<2048, 256, 0, stream>>>(Pun, vT, isum, out);
}

// Round 6
// 445.599 us; speedup vs baseline: 1.2344x; 1.0289x over previous
//
#include <hip/hip_runtime.h>
#include <hip/hip_bf16.h>
#include <stdint.h>

#define NEG_BIG (-1e24f)

typedef __attribute__((ext_vector_type(8))) short bf16x8;
typedef __attribute__((ext_vector_type(4))) float f32x4;

#define AS1 __attribute__((address_space(1)))
#define AS3 __attribute__((address_space(3)))

__device__ __forceinline__ void gload_lds16(const void* g, void* l) {
    __builtin_amdgcn_global_load_lds((AS1 unsigned*)g, (AS3 unsigned*)l, 16, 0, 0);
}

__device__ __forceinline__ unsigned short f2bf(float f) {
    union { float f; unsigned u; } v; v.f = f;
    return (unsigned short)((v.u + 0x7FFFu + ((v.u >> 16) & 1u)) >> 16);
}

// raw barrier: drain LDS ops only (NOT vmcnt -> in-flight global prefetch survives)
__device__ __forceinline__ void lds_barrier() {
    asm volatile("s_waitcnt lgkmcnt(0)" ::: "memory");
    __builtin_amdgcn_s_barrier();
    asm volatile("" ::: "memory");
}

// ---------------------------------------------------------------------------
// K0: detect padding_mask storage dtype from its bit patterns.
// flag: 0 = int32 {0,1}, 1 = uint8 bytes, 2 = float32 {0.0,1.0}
__global__ void detect_mask_kernel(const unsigned* pm, int* flag) {
    __shared__ int notI, notF;
    if (threadIdx.x == 0) { notI = 0; notF = 0; }
    __syncthreads();
    int li = 0, lf = 0;
    for (int i = threadIdx.x; i < 8192; i += 256) {
        unsigned v = pm[i];
        if (v > 1u) li = 1;
        if (v != 0u && v != 0x3F800000u) lf = 1;
    }
    if (li) atomicOr(&notI, 1);
    if (lf) atomicOr(&notF, 1);
    __syncthreads();
    if (threadIdx.x == 0) *flag = notI ? (notF ? 1 : 2) : 0;
}

// ---------------------------------------------------------------------------
// K1 (v5): 1024-thread blocks, 16 waves = 4 output-groups x 4 K-slices.
// Double-buffered LDS x-staging, one raw barrier per chunk, no vmcnt drains
// in the loop. Exact fp32 q/k. (verified round 4)
__global__ __launch_bounds__(1024, 8)
void qk_conv_kernel(const float* __restrict__ x,
                    const float* __restrict__ Wq, const float* __restrict__ bq,
                    const float* __restrict__ Wk, const float* __restrict__ bk,
                    const void* __restrict__ pm, const int* __restrict__ pmflag,
                    unsigned short* __restrict__ xbf,
                    float* __restrict__ qo, float* __restrict__ ko) {
    // union: 2 x-buffers [64*65] (33.3KB)  |  red[4][64][33] partials (33.8KB)
    __shared__ float smem[4 * 64 * 33];
    const int tid = threadIdx.x;
    const int r0 = blockIdx.x * 64;
    const int lane = tid & 63;
    const int wv = __builtin_amdgcn_readfirstlane(tid >> 6);  // 0..15
    const int g = wv & 3;              // 0,1 = q-halves; 2,3 = k-halves
    const int sl = wv >> 2;            // K-slice 0..3 (16 cols of each chunk)
    const int jb = (g & 1) * 8;
    const int d0 = sl * 16;
    const float* __restrict__ W = (g < 2) ? Wq : Wk;

    const int sr = tid >> 4;           // staging row 0..63
    const int sd = (tid & 15) * 4;     // staging col within chunk
    const float* __restrict__ xp = x + (size_t)(r0 + sr) * 1024 + sd;
    unsigned short* __restrict__ xbp = xbf + (size_t)(r0 + sr) * 1024 + sd;

    float acc[8];
#pragma unroll
    for (int j = 0; j < 8; j++) acc[j] = 0.f;

    // ---- prologue: stage chunk 0 into buf0, start chunk-1 load
    float4 xv = *(const float4*)xp;                    // chunk 0
    {
        uint2 pk;
        pk.x = (unsigned)f2bf(xv.x) | ((unsigned)f2bf(xv.y) << 16);
        pk.y = (unsigned)f2bf(xv.z) | ((unsigned)f2bf(xv.w) << 16);
        *(uint2*)xbp = pk;
        float* b0 = smem;                              // buf0
        b0[sr * 65 + sd + 0] = xv.x;
        b0[sr * 65 + sd + 1] = xv.y;
        b0[sr * 65 + sd + 2] = xv.z;
        b0[sr * 65 + sd + 3] = xv.w;
    }
    xv = *(const float4*)(xp + 64);                    // chunk 1 (in flight)
    lds_barrier();

    for (int t = 0; t < 16; t++) {
        // ---- stage chunk t+1 into buf[(t+1)&1] while computing chunk t
        if (t + 1 < 16) {
            uint2 pk;
            pk.x = (unsigned)f2bf(xv.x) | ((unsigned)f2bf(xv.y) << 16);
            pk.y = (unsigned)f2bf(xv.z) | ((unsigned)f2bf(xv.w) << 16);
            *(uint2*)(xbp + (t + 1) * 64) = pk;
            float* bw = smem + ((t + 1) & 1) * (64 * 65);
            bw[sr * 65 + sd + 0] = xv.x;
            bw[sr * 65 + sd + 1] = xv.y;
            bw[sr * 65 + sd + 2] = xv.z;
            bw[sr * 65 + sd + 3] = xv.w;
            if (t + 2 < 16) xv = *(const float4*)(xp + (t + 2) * 64);  // stays in flight
        }
        // ---- compute chunk t from buf[t&1]
        const float* __restrict__ xrow = smem + (t & 1) * (64 * 65) + lane * 65 + d0;
        const float* __restrict__ wrow = W + (size_t)(t * 64 + d0) * 16 + jb;
#pragma unroll
        for (int dd = 0; dd < 16; dd += 2) {
            const float x0 = xrow[dd];
            const float x1 = xrow[dd + 1];
            const float* __restrict__ w0 = wrow + dd * 16;
#pragma unroll
            for (int j = 0; j < 8; j++) acc[j] = fmaf(x0, w0[j], acc[j]);
#pragma unroll
            for (int j = 0; j < 8; j++) acc[j] = fmaf(x1, w0[16 + j], acc[j]);
        }
        lds_barrier();   // all waves done reading buf[t&1]; writes of t+1 committed
    }

    // ---- cross-slice reduction through LDS (stride 33 -> 2-way free banks)
    float* red = smem;
    const int cb = jb + (g >> 1) * 16;      // col base 0/8/16/24
    {
        float* rr = red + ((size_t)(sl * 64 + lane)) * 33 + cb;
#pragma unroll
        for (int j = 0; j < 8; j++) rr[j] = acc[j];
    }
    __syncthreads();

    // ---- epilogue: each thread finishes one q element + one k element
    const int row = tid >> 4;
    const int c = tid & 15;
    const int grow = r0 + row;
    const float qv = red[(size_t)row * 33 + c]
                   + red[(size_t)(64 + row) * 33 + c]
                   + red[(size_t)(128 + row) * 33 + c]
                   + red[(size_t)(192 + row) * 33 + c] + bq[c];
    qo[(size_t)grow * 16 + c] = qv;
    const int flag = *pmflag;
    bool mk;
    if (flag == 1) mk = ((const unsigned char*)pm)[grow] != 0;
    else           mk = ((const unsigned*)pm)[grow] != 0;
    float kv;
    if (mk) {
        kv = NEG_BIG;
    } else {
        kv = red[(size_t)row * 33 + 16 + c]
           + red[(size_t)(64 + row) * 33 + 16 + c]
           + red[(size_t)(128 + row) * 33 + 16 + c]
           + red[(size_t)(192 + row) * 33 + 16 + c] + bk[c];
    }
    ko[(size_t)grow * 16 + c] = kv;
}

// ---------------------------------------------------------------------------
// K2: WvT[n][k] = bf16(Wv[k][n])  (B-operand layout for MFMA GEMM)
__global__ void wvt_kernel(const float* __restrict__ Wv, unsigned short* __restrict__ WvT) {
    __shared__ float tile[32][33];
    const int k0 = blockIdx.x * 32, n0 = blockIdx.y * 32;
    const int tid = threadIdx.x;
#pragma unroll
    for (int i = 0; i < 4; i++) {
        int idx = i * 256 + tid;
        int r = idx >> 5, c = idx & 31;
        tile[r][c] = Wv[(size_t)(k0 + r) * 1024 + n0 + c];
    }
    __syncthreads();
#pragma unroll
    for (int i = 0; i < 4; i++) {
        int idx = i * 256 + tid;
        int r = idx >> 5, c = idx & 31;
        WvT[(size_t)(n0 + r) * 1024 + k0 + c] = f2bf(tile[c][r]);
    }
}

// ---------------------------------------------------------------------------
// K3 (v2): v = xbf @ WvT + bv, output DIRECTLY transposed: vT[b][e][s].
// T3-minimum double-buffered pipeline (verified round 3/4).
__global__ __launch_bounds__(256, 4)
void vgemm_kernel(const unsigned short* __restrict__ A,   // [32768][1024] bf16
                  const unsigned short* __restrict__ Bt,  // [1024][1024] bf16 (n-major)
                  const float* __restrict__ bias,
                  unsigned short* __restrict__ vTg) {     // [64][1024][512] bf16
    __shared__ __align__(16) unsigned short smem[17408];  // dbuf(16384) | vt(128*136)
    const int bid = blockIdx.x;
    const int c = bid & 7;
    const int g = bid >> 3;
    const int mt = c * 32 + (g >> 3);
    const int nt = g & 7;
    const int m0 = mt * 128;
    const int n0 = nt * 128;
    const int tid = threadIdx.x;
    const int lane = tid & 63;
    const int wave = tid >> 6;
    const int wm = (wave & 1) * 64;
    const int wn = (wave >> 1) * 64;
    const int l15 = lane & 15;
    const int quad = lane >> 4;
    const int arow = tid >> 2;
    const int acol = (tid & 3) * 8;
    const unsigned short* __restrict__ Ar0 = A + (size_t)(m0 + arow) * 1024 + acol;
    const unsigned short* __restrict__ Ar1 = A + (size_t)(m0 + 64 + arow) * 1024 + acol;
    const unsigned short* __restrict__ Br0 = Bt + (size_t)(n0 + arow) * 1024 + acol;
    const unsigned short* __restrict__ Br1 = Bt + (size_t)(n0 + 64 + arow) * 1024 + acol;
    f32x4 acc[4][4];
#pragma unroll
    for (int i = 0; i < 4; i++)
#pragma unroll
        for (int j = 0; j < 4; j++)
#pragma unroll
            for (int r = 0; r < 4; r++) acc[i][j][r] = 0.f;

    // prologue: stage tile 0 into buffer 0
    {
        unsigned short* As = smem;
        unsigned short* Bs = smem + 4096;
        gload_lds16(Ar0, As + tid * 8);
        gload_lds16(Ar1, As + 2048 + tid * 8);
        gload_lds16(Br0, Bs + tid * 8);
        gload_lds16(Br1, Bs + 2048 + tid * 8);
    }
    __syncthreads();
    int cur = 0;
    for (int t = 0; t < 32; t++) {
        if (t + 1 < 32) {
            const int kn = (t + 1) * 32;
            unsigned short* As = smem + (cur ^ 1) * 8192;
            unsigned short* Bs = As + 4096;
            gload_lds16(Ar0 + kn, As + tid * 8);
            gload_lds16(Ar1 + kn, As + 2048 + tid * 8);
            gload_lds16(Br0 + kn, Bs + tid * 8);
            gload_lds16(Br1 + kn, Bs + 2048 + tid * 8);
        }
        const unsigned short* As = smem + cur * 8192;
        const unsigned short* Bs = As + 4096;
        bf16x8 af[4], bfr[4];
#pragma unroll
        for (int i = 0; i < 4; i++) {
            af[i]  = *(const bf16x8*)(As + (wm + i * 16 + l15) * 32 + quad * 8);
            bfr[i] = *(const bf16x8*)(Bs + (wn + i * 16 + l15) * 32 + quad * 8);
        }
#pragma unroll
        for (int i = 0; i < 4; i++)
#pragma unroll
            for (int j = 0; j < 4; j++)
                acc[i][j] = __builtin_amdgcn_mfma_f32_16x16x32_bf16(af[i], bfr[j], acc[i][j], 0, 0, 0);
        __syncthreads();   // drains vmcnt (stage done) + lgkm (reads done)
        cur ^= 1;
    }
    // epilogue: bias + transpose through LDS, store vT coalesced
    unsigned short* vt = smem;  // reuse (safe: barrier above after last reads)
#pragma unroll
    for (int j = 0; j < 4; j++) {
        const int e_local = wn + j * 16 + l15;
        const float bb = bias[n0 + e_local];
#pragma unroll
        for (int i = 0; i < 4; i++) {
            const int s_base = wm + i * 16 + quad * 4;
            unsigned short h0 = f2bf(acc[i][j][0] + bb);
            unsigned short h1 = f2bf(acc[i][j][1] + bb);
            unsigned short h2 = f2bf(acc[i][j][2] + bb);
            unsigned short h3 = f2bf(acc[i][j][3] + bb);
            uint2 u;
            u.x = (unsigned)h0 | ((unsigned)h1 << 16);
            u.y = (unsigned)h2 | ((unsigned)h3 << 16);
            *(uint2*)(vt + e_local * 136 + s_base) = u;
        }
    }
    __syncthreads();
    const int b = m0 >> 9;
    const int sbase = m0 & 511;
#pragma unroll
    for (int p = 0; p < 8; p++) {
        const int idx = p * 256 + tid;
        const int e = idx >> 4;
        const int s8 = (idx & 15) * 8;
        uint4 val = *(const uint4*)(vt + e * 136 + s8);
        *(uint4*)(vTg + ((size_t)b * 1024 + n0 + e) * 512 + sbase + s8) = val;
    }
}

// ---------------------------------------------------------------------------
// K5a (v3): fp32 scores + 2-pass softmax with SAFE triangular skip.
// Full Kt staging. Max pass bounded to s<min(sbeg+256,cend) PLUS explicit
// future floor fmaxf(m, NEG_BIG) for tglob<511 -> M is bit-identical to the
// full-row max. A row is "pathological" iff M <= -1e20 (all causal-visible k
// masked & row-sum sign makes scores << -1e24): then exp(NEG_BIG-M) does NOT
// underflow and the upper triangle of P is nonzero. Block-wide patho flag
// forces full phases (and is exported for pv). For non-patho rows the
// skipped P region is EXACTLY 0 (exp underflow), so eliding it is exact.
__global__ __launch_bounds__(256, 2)
void score_kernel(const float* __restrict__ q, const float* __restrict__ k,
                  unsigned short* __restrict__ P, float* __restrict__ isum,
                  int* __restrict__ pflag) {
    __shared__ float Kt[512 * 16];
    __shared__ float Qt[128 * 16];
    __shared__ float redm[2][128];
    __shared__ float reds[2][128];
    __shared__ unsigned short Pt[2][64][132];
    __shared__ int pathoS;
    const int tid = threadIdx.x;
    const int b = blockIdx.y;
    const int t0 = blockIdx.x * 128;
    const int cend = t0 + 128;            // exclusive col bound for this row block
    if (tid == 0) pathoS = 0;
    {
        const float4* ks = (const float4*)(k + (size_t)b * 512 * 16);
        float4* kd = (float4*)Kt;
#pragma unroll
        for (int i = 0; i < 8; i++) kd[i * 256 + tid] = ks[i * 256 + tid];
        const float4* qs = (const float4*)(q + ((size_t)b * 512 + t0) * 16);
        float4* qd = (float4*)Qt;
#pragma unroll
        for (int i = 0; i < 2; i++) qd[i * 256 + tid] = qs[i * 256 + tid];
    }
    __syncthreads();
    const int row = tid & 127;
    const int half = tid >> 7;
    const int sbeg = half * 256;
    const int send = (sbeg + 256 < cend) ? (sbeg + 256) : cend;  // triangular bound
    const int tglob = t0 + row;
    float qr[16];
#pragma unroll
    for (int j = 0; j < 16; j++) qr[j] = Qt[row * 16 + j];

    float m = -INFINITY;
    for (int s = sbeg; s < send; s++) {
        const float* kk = Kt + s * 16;
        float dot = 0.f;
#pragma unroll
        for (int j = 0; j < 16; j++) dot = fmaf(qr[j], kk[j], dot);
        float sc = (s > tglob) ? NEG_BIG : dot * 4.0f;
        m = fmaxf(m, sc);
    }
    // future-cols floor: cols > tglob all carry NEG_BIG in the full-row max
    if (tglob < 511) m = fmaxf(m, NEG_BIG);
    redm[half][row] = m;
    __syncthreads();
    const float M = fmaxf(redm[0][row], redm[1][row]);
    if (half == 0 && M <= -1e20f) pathoS = 1;   // benign same-value race
    __syncthreads();
    const int patho = pathoS;
    float sum = 0.f;
    for (int ph = 0; ph < 4; ph++) {
        const int c0 = sbeg + ph * 64;
        if (c0 < cend || patho) {        // wave-uniform guard; barriers unconditional
            for (int s = c0; s < c0 + 64; s++) {
                const float* kk = Kt + s * 16;
                float dot = 0.f;
#pragma unroll
                for (int j = 0; j < 16; j++) dot = fmaf(qr[j], kk[j], dot);
                float sc = (s > tglob) ? NEG_BIG : dot * 4.0f;
                float p = __expf(sc - M);
                sum += p;
                Pt[half][s - c0][row] = f2bf(p);
            }
        }
        __syncthreads();
#pragma unroll
        for (int i = 0; i < 8; i++) {
            int li = i * 256 + tid;
            int h = li >> 10;
            int r = (li >> 3) & 127;
            int cg = li & 7;
            if (h * 256 + ph * 64 < cend || patho) {   // store all readable regions
                union { unsigned short u[8]; uint4 v; } tmp;
#pragma unroll
                for (int j = 0; j < 8; j++) tmp.u[j] = Pt[h][cg * 8 + j][r];
                *(uint4*)(P + ((size_t)(b * 512 + t0 + r)) * 512 + h * 256 + ph * 64 + cg * 8) = tmp.v;
            }
        }
        __syncthreads();
    }
    reds[half][row] = sum;
    __syncthreads();
    if (half == 0) {
        float tot = reds[0][row] + reds[1][row];
        isum[(size_t)b * 512 + tglob] = 1.0f / tot;
    }
    if (tid == 0) pflag[b * 4 + blockIdx.x] = patho;
}

// ---------------------------------------------------------------------------
// K5b (v4): out[b][t][e] = (P[b] @ vT[b]^T)[t][e] * isum[b][t]
// Triangular skip gated by the patho flag: non-patho row-blocks read only
// k < m0+128 (P beyond is exactly 0); patho blocks do the full K=512.
__global__ __launch_bounds__(256, 4)
void pv_kernel(const unsigned short* __restrict__ P,
               const unsigned short* __restrict__ vT,
               const float* __restrict__ isum,
               const int* __restrict__ pflag,
               float* __restrict__ out) {
    __shared__ __align__(16) unsigned short smem[16384];  // dbuf 2x(As+Bs)
    const int bid = blockIdx.x;
    const int c = bid & 7;
    const int g = bid >> 3;
    const int b = c * 8 + (g >> 5);
    const int rem = g & 31;
    const int m0 = (rem >> 3) * 128;
    const int n0 = (rem & 7) * 128;
    const int patho = pflag[b * 4 + (m0 >> 7)];
    const int ntiles = patho ? 16 : ((m0 >> 5) + 4);   // k < m0+128 unless patho
    const int tid = threadIdx.x;
    const int lane = tid & 63;
    const int wave = tid >> 6;
    const int wm = (wave & 1) * 64;
    const int wn = (wave >> 1) * 64;
    const int l15 = lane & 15;
    const int quad = lane >> 4;
    const int arow = tid >> 2;
    const int acol = (tid & 3) * 8;
    const unsigned short* __restrict__ Ar0 = P + (size_t)b * 512 * 512 + (size_t)(m0 + arow) * 512 + acol;
    const unsigned short* __restrict__ Ar1 = Ar0 + (size_t)64 * 512;
    const unsigned short* __restrict__ Br0 = vT + (size_t)b * 1024 * 512 + (size_t)(n0 + arow) * 512 + acol;
    const unsigned short* __restrict__ Br1 = Br0 + (size_t)64 * 512;
    f32x4 acc[4][4];
#pragma unroll
    for (int i = 0; i < 4; i++)
#pragma unroll
        for (int j = 0; j < 4; j++)
#pragma unroll
            for (int r = 0; r < 4; r++) acc[i][j][r] = 0.f;

    {
        unsigned short* As = smem;
        unsigned short* Bs = smem + 4096;
        gload_lds16(Ar0, As + tid * 8);
        gload_lds16(Ar1, As + 2048 + tid * 8);
        gload_lds16(Br0, Bs + tid * 8);
        gload_lds16(Br1, Bs + 2048 + tid * 8);
    }
    __syncthreads();
    int cur = 0;
    for (int t = 0; t < ntiles; t++) {
        if (t + 1 < ntiles) {
            const int kn = (t + 1) * 32;
            unsigned short* As = smem + (cur ^ 1) * 8192;
            unsigned short* Bs = As + 4096;
            gload_lds16(Ar0 + kn, As + tid * 8);
            gload_lds16(Ar1 + kn, As + 2048 + tid * 8);
            gload_lds16(Br0 + kn, Bs + tid * 8);
            gload_lds16(Br1 + kn, Bs + 2048 + tid * 8);
        }
        const unsigned short* As = smem + cur * 8192;
        const unsigned short* Bs = As + 4096;
        bf16x8 af[4], bfr[4];
#pragma unroll
        for (int i = 0; i < 4; i++) {
            af[i]  = *(const bf16x8*)(As + (wm + i * 16 + l15) * 32 + quad * 8);
            bfr[i] = *(const bf16x8*)(Bs + (wn + i * 16 + l15) * 32 + quad * 8);
        }
#pragma unroll
        for (int i = 0; i < 4; i++)
#pragma unroll
            for (int j = 0; j < 4; j++)
                acc[i][j] = __builtin_amdgcn_mfma_f32_16x16x32_bf16(af[i], bfr[j], acc[i][j], 0, 0, 0);
        __syncthreads();
        cur ^= 1;
    }
#pragma unroll
    for (int i = 0; i < 4; i++) {
#pragma unroll
        for (int r = 0; r < 4; r++) {
            const int trow = m0 + wm + i * 16 + quad * 4 + r;
            const float sc = isum[(size_t)b * 512 + trow];
#pragma unroll
            for (int j = 0; j < 4; j++) {
                const int ncol = n0 + wn + j * 16 + l15;
                out[((size_t)b * 512 + trow) * 1024 + ncol] = acc[i][j][r] * sc;
            }
        }
    }
}

// ---------------------------------------------------------------------------
extern "C" void kernel_launch(void* const* d_in, const int* in_sizes, int n_in,
                              void* d_out, int out_size, void* d_ws, size_t ws_size,
                              hipStream_t stream) {
    const float* x  = (const float*)d_in[0];
    const void*  pm = d_in[1];
    const float* Wq = (const float*)d_in[2];
    const float* bq = (const float*)d_in[3];
    const float* Wk = (const float*)d_in[4];
    const float* bk = (const float*)d_in[5];
    const float* Wv = (const float*)d_in[6];
    const float* bv = (const float*)d_in[7];
    float* out = (float*)d_out;

    char* ws = (char*)d_ws;
    const size_t MB = 1024 * 1024;
    unsigned short* xbf = (unsigned short*)ws;                 // 64MB (K1->K3)
    unsigned short* Pun = (unsigned short*)ws;                 // 32MB overlay (K5a->K5b, after xbf dead)
    unsigned short* vT  = (unsigned short*)(ws + 64 * MB);     // 64MB
    float* qbuf = (float*)(ws + 128 * MB);                     // 2MB
    float* kbuf = (float*)(ws + 130 * MB);                     // 2MB
    unsigned short* WvT = (unsigned short*)(ws + 132 * MB);    // 2MB
    float* isum = (float*)(ws + 134 * MB);                     // 128KB
    int* flag   = (int*)(ws + 135 * MB);
    int* pflag  = (int*)(ws + 135 * MB + 256);                 // 64*4 ints

    detect_mask_kernel<<<1, 256, 0, stream>>>((const unsigned*)pm, flag);
    qk_conv_kernel<<<512, 1024, 0, stream>>>(x, Wq, bq, Wk, bk, pm, flag, xbf, qbuf, kbuf);
    wvt_kernel<<<dim3(32, 32), 256, 0, stream>>>(Wv, WvT);
    vgemm_kernel<<<2048, 256, 0, stream>>>(xbf, WvT, bv, vT);
    score_kernel<<<dim3(4, 64), 256, 0, stream>>>(qbuf, kbuf, Pun, isum, pflag);
    pv_kernel<<<2048, 256, 0, stream>>>(Pun, vT, isum, pflag, out);
}